// Round 10
// baseline (525.937 us; speedup 1.0000x reference)
//
#include <hip/hip_runtime.h>
#include <math.h>

// VectorQuantizer, MFMA filter + exact-fp32 rescore.  N=32768 rows x K=8192
// codes, dim 64.
//   R5 116us (LDS, 2 sweeps) / R8 220 (scattered global B) / R9 127us vq_main
//   (permuted coalesced B; but VGPR=64 => JIT loads, ~200cyc exposed L2
//   latency per t-group, and the 2nd sweep doubles all work).
// R10: SINGLE sweep + lagged running threshold + explicit register pipeline.
//   - Per-row running max kept in-wave; threshold refreshed every 8 t-groups
//     via 4x shfl_xor (row's 16 code-columns live across lanes s=0..15).
//   - Emission uses the LAGGED threshold (only ever rises) -> emitted set is
//     a superset of the final-threshold set -> exact-argmin guarantee intact.
//   - t-groups 0..7 emit nothing (no threshold yet); re-scanned at tt=64..71
//     (t_act = tt&63) after the full-slice threshold exists.  smax updates on
//     re-scan are idempotent (fmax with same values).
//   - fb[4][2] register pipeline, unroll 8, static indices: ~4-iteration
//     (~300cyc) load lookahead > ~200cyc L2 latency.
//
// Exact numpy-fp32 semantics preserved (absmax 0 since R2 — DO NOT TOUCH):
//   S = sequential __fmaf_rn chain c=0..63; normx = numpy pairwise(n=64);
//   d = fl(normx - 2S) (2S exact); argmin = lowest index on ties.
// bf16 MFMA S~ error <= ~2e-5; exact-d quantization ~3.8e-6: codes with
// S~ >= rowmax - HALF_DELTA (4e-5) are a guaranteed superset of the exact
// argmin; rescored bit-exactly; (d_bits<<13|k) u64 atomicMin implements
// value-then-lowest-index.  8 k-slices merge in vq_out.

#define DIM      64
#define NCODE    8192
#define NROWS    32768
#define RPB      256               // rows per block: 4 waves x 4 row-tiles x 16
#define KQ       1024              // codes per block (gridDim.y = 8)
#define NT       (KQ / 16)         // 64 t-groups of 16 codes
#define HALF_DELTA 4.0e-5f
#define CAND_CAP 4096

typedef __attribute__((ext_vector_type(8))) short frag8;   // 8 bf16
typedef __attribute__((ext_vector_type(4))) float f32x4;

__device__ __forceinline__ unsigned short f2bf_rne(float f) {
  unsigned u = __float_as_uint(f);
  return (unsigned short)((u + 0x7FFFu + ((u >> 16) & 1u)) >> 16);
}

// ---- kernel 0: codebook fp32 -> bf16 (RNE), PERMUTED to fragment order ----
// 16B chunk (g,h,s,q) = e[g*16+s][h*32+q*8 .. +8)  ->  index g*128+h*64+s*4+q.
__global__ __launch_bounds__(256) void cvt_emb(const float* __restrict__ emb,
                                               unsigned short* __restrict__ ebp) {
  const int chunk = blockIdx.x * 256 + threadIdx.x;   // 0..65535
  const int i = chunk * 8;                            // source float index
  const int k = i >> 6, c = i & 63;
  const int h = c >> 5, q = (c >> 3) & 3;
  const int g = k >> 4, s = k & 15;
  const float4 a = *(const float4*)(emb + i);
  const float4 b2 = *(const float4*)(emb + i + 4);
  union { unsigned short u[8]; uint4 v; } o;
  o.u[0] = f2bf_rne(a.x);  o.u[1] = f2bf_rne(a.y);
  o.u[2] = f2bf_rne(a.z);  o.u[3] = f2bf_rne(a.w);
  o.u[4] = f2bf_rne(b2.x); o.u[5] = f2bf_rne(b2.y);
  o.u[6] = f2bf_rne(b2.z); o.u[7] = f2bf_rne(b2.w);
  const int dst = g * 128 + h * 64 + s * 4 + q;
  *(uint4*)(ebp + (size_t)dst * 8) = o.v;
}

// ---- kernel 1: per (256-row group, 1024-code slice), single sweep ----
__global__ __launch_bounds__(256, 4) void vq_main(
    const float* __restrict__ x, const float* __restrict__ emb,
    const unsigned short* __restrict__ ebp,
    unsigned long long* __restrict__ wsbest)
{
  __shared__ float s_normx[RPB];
  __shared__ unsigned long long s_best[RPB];
  __shared__ unsigned s_cand[CAND_CAP];        // (row_l<<10 | k_local)
  __shared__ int s_cnt;

  const int tid  = threadIdx.x;
  const int lane = tid & 63;
  const int wave = tid >> 6;
  const int s    = lane & 15;                  // MFMA m / n index
  const int q    = lane >> 4;                  // MFMA quad
  const int rowbase = blockIdx.x * RPB;
  const int kbase   = blockIdx.y * KQ;
  const int b    = rowbase >> 10;
  const int hw0  = rowbase & 1023;             // multiple of 256; one image b
  const float* xb = x + (size_t)b * (DIM * 1024);

  if (tid == 0) s_cnt = 0;
  s_best[tid] = ~0ull;

  // normx — numpy pairwise_sum(n=64) bit-exact, streamed 8 loads at a time.
  {
    float r8[8];
#pragma unroll
    for (int m = 0; m < 8; ++m) {
#pragma unroll
      for (int j = 0; j < 8; ++j) {
        const float v = xb[(size_t)(m * 8 + j) * 1024 + hw0 + tid];
        const float pv = __fmul_rn(v, v);
        r8[j] = (m == 0) ? pv : __fadd_rn(r8[j], pv);
      }
    }
    const float t0 = __fadd_rn(r8[0], r8[1]), t1 = __fadd_rn(r8[2], r8[3]);
    const float t2 = __fadd_rn(r8[4], r8[5]), t3 = __fadd_rn(r8[6], r8[7]);
    s_normx[tid] = __fadd_rn(__fadd_rn(t0, t1), __fadd_rn(t2, t3));
  }

  // A-frags: wave owns 64 rows = 4 row-tiles of 16.  A[m=s][k=q*8+j].
  frag8 afr[4][2];
#pragma unroll
  for (int rt = 0; rt < 4; ++rt) {
    const float* xp = xb + hw0 + wave * 64 + rt * 16 + s;
#pragma unroll
    for (int h = 0; h < 2; ++h) {
      frag8 f;
#pragma unroll
      for (int j = 0; j < 8; ++j)
        f[j] = (short)f2bf_rne(xp[(size_t)(h * 32 + q * 8 + j) * 1024]);
      afr[rt][h] = f;
    }
  }

  // B-frags from permuted codebook: t-group g -> b0 = pp[g*128], b1 = +64.
  const frag8* pp = (const frag8*)ebp + (size_t)(kbase >> 4) * 128 + s * 4 + q;

  f32x4 smax[4];
#pragma unroll
  for (int rt = 0; rt < 4; ++rt) smax[rt] = (f32x4){-1e30f, -1e30f, -1e30f, -1e30f};
  float thr[4][4];
#pragma unroll
  for (int rt = 0; rt < 4; ++rt)
#pragma unroll
    for (int r = 0; r < 4; ++r) thr[rt][r] = INFINITY;   // no emission pre-refresh

  // register pipeline: 4 slots, loaded 4 iterations ahead
  frag8 fb[4][2];
#pragma unroll
  for (int p = 0; p < 4; ++p) { fb[p][0] = pp[p * 128]; fb[p][1] = pp[p * 128 + 64]; }

  // tt 0..63: groups 0..63 (emit from tt>=8).  tt 64..71: re-scan groups 0..7
  // with the full threshold.  t_act = tt & 63 makes prefetch/use consistent.
#pragma unroll 8
  for (int tt = 0; tt < 72; ++tt) {
    if ((tt & 7) == 0 && tt > 0) {             // refresh lagged row thresholds
#pragma unroll
      for (int rt = 0; rt < 4; ++rt)
#pragma unroll
        for (int r = 0; r < 4; ++r) {
          float v = smax[rt][r];
          v = fmaxf(v, __shfl_xor(v, 1, 64));
          v = fmaxf(v, __shfl_xor(v, 2, 64));
          v = fmaxf(v, __shfl_xor(v, 4, 64));
          v = fmaxf(v, __shfl_xor(v, 8, 64));
          thr[rt][r] = v - HALF_DELTA;
        }
    }
    const int slot = tt & 3;
    const frag8 b0 = fb[slot][0];
    const frag8 b1 = fb[slot][1];
    {
      const int ta = (tt + 4) & 63;            // prefetch 4 groups ahead
      fb[slot][0] = pp[ta * 128];
      fb[slot][1] = pp[ta * 128 + 64];
    }
    const int kl = (tt & 63) * 16 + s;
    const bool emit = (tt >= 8);
#pragma unroll
    for (int rt = 0; rt < 4; ++rt) {
      f32x4 d = {0.f, 0.f, 0.f, 0.f};
      d = __builtin_amdgcn_mfma_f32_16x16x32_bf16(afr[rt][0], b0, d, 0, 0, 0);
      d = __builtin_amdgcn_mfma_f32_16x16x32_bf16(afr[rt][1], b1, d, 0, 0, 0);
#pragma unroll
      for (int r = 0; r < 4; ++r) {
        smax[rt][r] = fmaxf(smax[rt][r], d[r]);          // idempotent on re-scan
        if (emit && d[r] >= thr[rt][r]) {
          const int pos = atomicAdd(&s_cnt, 1);
          if (pos < CAND_CAP)
            s_cand[pos] = ((unsigned)(wave * 64 + rt * 16 + q * 4 + r) << 10) | (unsigned)kl;
        }
      }
    }
  }
  __syncthreads();

  // ---- exact rescore of candidates (bit-exact numpy fp32 pipeline) ----
  const int cnt = min(s_cnt, CAND_CAP);
  for (int i = tid; i < cnt; i += 256) {
    const unsigned e = s_cand[i];
    const int row_l = (int)(e >> 10);
    const int kg = kbase + (int)(e & 0x3FFu);
    const float* ep = emb + (size_t)kg * DIM;
    const float* xp = xb + hw0 + row_l;
    float S = 0.f;
#pragma unroll
    for (int c = 0; c < DIM; ++c) S = __fmaf_rn(xp[(size_t)c * 1024], ep[c], S);
    const float dd = __fsub_rn(s_normx[row_l], __fadd_rn(S, S));
    const unsigned long long pack =
        ((unsigned long long)__float_as_uint(dd) << 13) | (unsigned long long)kg;
    atomicMin(&s_best[row_l], pack);
  }
  __syncthreads();

  wsbest[(size_t)(rowbase + tid) * 8 + blockIdx.y] = s_best[tid];
}

// ---- kernel 2: merge slices, write indices + gather z_q ----
__global__ __launch_bounds__(256) void vq_out(
    const float* __restrict__ emb, const unsigned long long* __restrict__ wsbest,
    float* __restrict__ zq, float* __restrict__ idx_out)
{
  const int row = blockIdx.x * 256 + threadIdx.x;
  unsigned long long p = wsbest[(size_t)row * 8];
#pragma unroll
  for (int j = 1; j < 8; ++j) {
    const unsigned long long pj = wsbest[(size_t)row * 8 + j];
    if (pj < p) p = pj;                        // d-major, then lowest k
  }
  const int k = (int)(p & 0x1FFFull);
  idx_out[row] = (float)k;
  const int b = row >> 10, hw = row & 1023;
  const float* ep = emb + (size_t)k * DIM;
  float* zp = zq + (size_t)b * (DIM * 1024) + hw;
#pragma unroll
  for (int c = 0; c < DIM; ++c) zp[(size_t)c * 1024] = ep[c];
}

extern "C" void kernel_launch(void* const* d_in, const int* in_sizes, int n_in,
                              void* d_out, int out_size, void* d_ws, size_t ws_size,
                              hipStream_t stream) {
  const float* x   = (const float*)d_in[0];   // [32, 64, 32, 32] fp32
  const float* emb = (const float*)d_in[1];   // [8192, 64] fp32

  float* zq      = (float*)d_out;
  float* idx_out = zq + (size_t)NROWS * DIM;

  unsigned short*     ebp    = (unsigned short*)d_ws;                          // 1 MB (permuted)
  unsigned long long* wsbest = (unsigned long long*)((char*)d_ws + (1 << 20)); // 2 MB

  cvt_emb<<<dim3(256), 256, 0, stream>>>(emb, ebp);
  vq_main<<<dim3(NROWS / RPB, NCODE / KQ), 256, 0, stream>>>(x, emb, ebp, wsbest);
  vq_out<<<dim3(NROWS / 256), 256, 0, stream>>>(emb, wsbest, zq, idx_out);
}